// Round 12
// baseline (253.264 us; speedup 1.0000x reference)
//
#include <hip/hip_runtime.h>
#include <hip/hip_bf16.h>

// GCNConv + ReLU: out = relu( (A_norm @ (x W)) + b ), A_norm = D^-1/2 (A + I) D^-1/2
// Round 18: single change vs round-17 (251.9 us, best): pin gemm's B panel in
// VGPRs. Evidence: round-8 profile showed gemm VGPR_Count=84 although Bfrag
// declares 128 VGPRs -> compiler sinks the loads and re-streams B from L2 in
// every sub-loop; each 32-MFMA chain then stalls ~300cyc on B with only 8
// waves/CU to hide it (MfmaUtil 5.4%). Empty asm volatile("+v") after the load
// loop forces materialization (rule: asm keeps values live); ~190 VGPR fits
// the 256 cap at launch_bounds(256,2). B loads once per block; compute phase
// becomes ds_read+MFMA only. Aggregate: ACCEPTED at hardware floor -- 3
// structurally different gathers (rounds 2/5/17) all ~107-115 us => bound by
// in-flight-line capacity x latency (~0.2 lines/cyc/CU), not instrs or bytes.

#define FEATS 256
#define MAXBUCK 200   // >= (50000+255)>>8 = 196
#define P1_CAP 64     // LDS slots per bucket per 4096-edge chunk (mean ~21)
#define BCAP 10240    // temp capacity per bucket (mean 8192, ~22 sigma)

typedef __bf16 bf16x8 __attribute__((ext_vector_type(8)));
typedef float f32x4 __attribute__((ext_vector_type(4)));
typedef unsigned u32x4 __attribute__((ext_vector_type(4)));

__device__ __forceinline__ unsigned short f2bf(float f) {  // RNE
  unsigned u = __float_as_uint(f);
  u += 0x7fffu + ((u >> 16) & 1u);
  return (unsigned short)(u >> 16);
}
__device__ __forceinline__ float bflo(unsigned u) { return __uint_as_float(u << 16); }
__device__ __forceinline__ float bfhi(unsigned u) { return __uint_as_float(u & 0xFFFF0000u); }

// ---------------- CSR build ----------------

// pass1: bin packed edges (dst<<16|src) by dst>>8. 1024 threads, 4096 edges/block.
__global__ __launch_bounds__(1024) void pass1_bin(const int* __restrict__ src,
                                                  const int* __restrict__ dst,
                                                  int E, int nbuck,
                                                  int* __restrict__ gcursor,
                                                  unsigned* __restrict__ temp) {
  __shared__ unsigned lbuf[MAXBUCK * P1_CAP];  // 51.2 KB
  __shared__ int lcnt[MAXBUCK];
  __shared__ int lbase[MAXBUCK];
  const int tid = threadIdx.x;
  for (int i = tid; i < nbuck; i += 1024) lcnt[i] = 0;
  __syncthreads();

  const int e0 = blockIdx.x * 4096;
  #pragma unroll
  for (int i = 0; i < 4; ++i) {
    int e = e0 + i * 1024 + tid;
    if (e < E) {
      unsigned d = (unsigned)dst[e];
      unsigned p = (d << 16) | (unsigned)src[e];
      int b = (int)(d >> 8);
      int pos = atomicAdd(&lcnt[b], 1);
      if (pos < P1_CAP) {
        lbuf[b * P1_CAP + pos] = p;
      } else {  // rare spill: direct global scatter
        int gp = atomicAdd(&gcursor[b], 1);
        temp[(size_t)b * BCAP + gp] = p;
      }
    }
  }
  __syncthreads();
  if (tid < nbuck) {
    int c = lcnt[tid]; if (c > P1_CAP) c = P1_CAP;
    lcnt[tid] = c;
    lbase[tid] = atomicAdd(&gcursor[tid], c);
  }
  __syncthreads();
  for (int i = tid; i < nbuck * P1_CAP; i += 1024) {
    int b = i >> 6, j = i & (P1_CAP - 1);
    if (j < lcnt[b]) temp[(size_t)b * BCAP + lbase[b] + j] = lbuf[i];
  }
}

// exclusive scan over bucket counts (nbuck <= 256), one block
__global__ __launch_bounds__(256) void scan_buckets(const int* __restrict__ gcursor,
                                                    int* __restrict__ bbase,
                                                    int* __restrict__ row_ptr,
                                                    int nbuck, int n) {
  __shared__ int tmp[256];
  int t = threadIdx.x;
  int v = (t < nbuck) ? min(gcursor[t], BCAP) : 0;
  tmp[t] = v;
  __syncthreads();
  #pragma unroll
  for (int off = 1; off < 256; off <<= 1) {
    int x = (t >= off) ? tmp[t - off] : 0;
    __syncthreads();
    tmp[t] += x;
    __syncthreads();
  }
  if (t < nbuck) bbase[t] = tmp[t] - v;
  if (t == 0) row_ptr[n] = tmp[255];
}

// pass2: per-bucket local CSR. 1024 threads.
__global__ __launch_bounds__(1024) void pass2_csr(const unsigned* __restrict__ temp,
                                                  const int* __restrict__ gcursor,
                                                  const int* __restrict__ bbase,
                                                  unsigned short* __restrict__ csr16,
                                                  int* __restrict__ row_ptr,
                                                  float* __restrict__ dinv, int n) {
  __shared__ unsigned ebuf[BCAP];          // 40 KB
  __shared__ unsigned short sorted[BCAP];  // 20 KB
  __shared__ int hist[256], scn[256], sexcl[256], ofs[256];
  const int b = blockIdx.x;
  const int tid = threadIdx.x;
  int cnt = gcursor[b]; if (cnt > BCAP) cnt = BCAP;
  const int base = bbase[b];
  const unsigned* tp = temp + (size_t)b * BCAP;

  if (tid < 256) { hist[tid] = 0; ofs[tid] = 0; }
  for (int i = tid; i < cnt; i += 1024) ebuf[i] = tp[i];
  __syncthreads();
  for (int i = tid; i < cnt; i += 1024) atomicAdd(&hist[(ebuf[i] >> 16) & 255], 1);
  __syncthreads();

  if (tid < 256) scn[tid] = hist[tid];
  __syncthreads();
  #pragma unroll
  for (int off = 1; off < 256; off <<= 1) {
    int x = 0;
    if (tid < 256 && tid >= off) x = scn[tid - off];
    __syncthreads();
    if (tid < 256) scn[tid] += x;
    __syncthreads();
  }
  if (tid < 256) {
    int v = hist[tid];
    int excl = scn[tid] - v;
    sexcl[tid] = excl;
    int node = (b << 8) + tid;
    if (node < n) {
      row_ptr[node] = base + excl;
      dinv[node] = rsqrtf((float)(v + 1));  // +1 self loop
    }
  }
  __syncthreads();

  for (int i = tid; i < cnt; i += 1024) {
    unsigned e = ebuf[i];
    int dl = (int)((e >> 16) & 255);
    int pos = sexcl[dl] + atomicAdd(&ofs[dl], 1);
    sorted[pos] = (unsigned short)(e & 0xFFFFu);
  }
  __syncthreads();
  for (int i = tid; i < cnt; i += 1024) csr16[base + i] = sorted[i];
}

// ---------------- Wt build + misc init (fused): Wt[n][k] = bf16(W[k][n]) ----------------
// blocks 0..255: transpose W; block 256: zero gcursor + zero xwp sentinel row n.

__global__ __launch_bounds__(256) void wt_init(const float* __restrict__ W,
                                               unsigned short* __restrict__ Wt,
                                               int* __restrict__ gcursor, int nbuck,
                                               unsigned* __restrict__ xwp_srow) {
  const int bk = (int)blockIdx.x;
  const int t  = (int)threadIdx.x;
  if (bk < 256) {
    Wt[t * FEATS + bk] = f2bf(W[bk * FEATS + t]);
  } else {
    if (t < nbuck) gcursor[t] = 0;
    if (t < 128) xwp_srow[t] = 0;  // 512 B sentinel row = 128 uints
  }
}

// ---------------- MFMA GEMM: xwp[r][:] = bf16( (x @ W)[r][:] * dinv[r] ) ----------------
// Block = 64 rows x 256 cols, 4 waves; B panel PINNED in 128 VGPRs/wave via
// empty asm (round-8 profile: compiler chose VGPR=84 => it was re-streaming B
// from L2 per sub-loop); A converted cooperatively into pre-fragmented LDS;
// C staged through a XOR-swizzled 32 KB LDS tile, written as 512 B rows.

__global__ __launch_bounds__(256, 2) void gemm_mfma(const float* __restrict__ x,
                                                    const unsigned short* __restrict__ Wt,
                                                    const float* __restrict__ dinv,
                                                    unsigned short* __restrict__ xwp, int M) {
  __shared__ bf16x8 A_lds[32 * 64];            // 32 KB: [sub*8+kc][lane]
  __shared__ unsigned short C_lds[64 * 256];   // 32 KB: [row][swizzled col]
  const int wv   = (int)(threadIdx.x >> 6);
  const int lane = (int)(threadIdx.x & 63);
  const int lm   = lane & 15;
  const int quad = lane >> 4;
  const int m0   = (int)blockIdx.x * 64;

  // B panel: load once, then FORCE materialization so it stays resident.
  u32x4 Bfrag[4][8];
  #pragma unroll
  for (int ct = 0; ct < 4; ++ct) {
    const unsigned short* wrow = Wt + (size_t)(wv * 64 + ct * 16 + lm) * FEATS + quad * 8;
    #pragma unroll
    for (int kc = 0; kc < 8; ++kc)
      Bfrag[ct][kc] = *(const u32x4*)(wrow + kc * 32);
  }
  #pragma unroll
  for (int ct = 0; ct < 4; ++ct)
    #pragma unroll
    for (int kc = 0; kc < 8; ++kc)
      asm volatile("" : "+v"(Bfrag[ct][kc]));

  {
    int arow = m0 + wv * 16 + lm; if (arow >= M) arow = M - 1;
    const float* xrow = x + (size_t)arow * FEATS + quad * 8;
    #pragma unroll
    for (int kc = 0; kc < 8; ++kc) {
      const float4 f0 = *(const float4*)(xrow + kc * 32);
      const float4 f1 = *(const float4*)(xrow + kc * 32 + 4);
      union { bf16x8 v; unsigned short u[8]; } a;
      a.u[0] = f2bf(f0.x); a.u[1] = f2bf(f0.y); a.u[2] = f2bf(f0.z); a.u[3] = f2bf(f0.w);
      a.u[4] = f2bf(f1.x); a.u[5] = f2bf(f1.y); a.u[6] = f2bf(f1.z); a.u[7] = f2bf(f1.w);
      A_lds[(wv * 8 + kc) * 64 + lane] = a.v;
    }
  }
  __syncthreads();

  #pragma unroll
  for (int sub = 0; sub < 4; ++sub) {
    bf16x8 Af[8];
    #pragma unroll
    for (int kc = 0; kc < 8; ++kc) Af[kc] = A_lds[(sub * 8 + kc) * 64 + lane];

    f32x4 acc[4];
    #pragma unroll
    for (int ct = 0; ct < 4; ++ct) acc[ct] = (f32x4){0.f, 0.f, 0.f, 0.f};

    #pragma unroll
    for (int kc = 0; kc < 8; ++kc) {
      #pragma unroll
      for (int ct = 0; ct < 4; ++ct)
        acc[ct] = __builtin_amdgcn_mfma_f32_16x16x32_bf16(
            Af[kc], __builtin_bit_cast(bf16x8, Bfrag[ct][kc]), acc[ct], 0, 0, 0);
    }

    #pragma unroll
    for (int r = 0; r < 4; ++r) {
      const int lrow = sub * 16 + quad * 4 + r;
      int grow = m0 + lrow; if (grow >= M) grow = M - 1;
      const float dd = dinv[grow];
      #pragma unroll
      for (int ct = 0; ct < 4; ++ct)
        C_lds[lrow * 256 + wv * 64 + ((ct ^ quad) << 4) + lm] = f2bf(acc[ct][r] * dd);
    }
  }
  __syncthreads();

  // coalesced writeout: 8 rounds x 8 rows; 32 threads/row x 16 B = 512 B/row.
  const int t  = (int)(threadIdx.x & 31);
  const int r8 = (int)(threadIdx.x >> 5);  // 0..7
  #pragma unroll
  for (int j = 0; j < 8; ++j) {
    const int lrow = j * 8 + r8;
    const int grow = m0 + lrow;
    if (grow < M) {
      const int qr = (lrow >> 2) & 3;
      const unsigned short* srcp = C_lds + lrow * 256 + (((t * 16) ^ (qr << 5)) >> 1);
      *(uint4*)(xwp + (size_t)grow * FEATS + t * 8) = *(const uint4*)srcp;
    }
  }
}

// ---------------- aggregation: paired-edge uint4 gathers (round-17, accepted) ----------------

#define AGG_ACC(J0, CNT) do {                                                      \
    uint4 vv[CNT];                                                                 \
    _Pragma("unroll")                                                              \
    for (int j = 0; j < (CNT); ++j) {                                              \
      int sj = __shfl(s, (J0) + 2 * j + half);                                     \
      vv[j] = *(const uint4*)(xb + ((size_t)sj << 8));                             \
    }                                                                              \
    _Pragma("unroll")                                                              \
    for (int j = 0; j < (CNT); ++j) {                                              \
      a0 += bflo(vv[j].x); a1 += bfhi(vv[j].x);                                    \
      a2 += bflo(vv[j].y); a3 += bfhi(vv[j].y);                                    \
      a4 += bflo(vv[j].z); a5 += bfhi(vv[j].z);                                    \
      a6 += bflo(vv[j].w); a7 += bfhi(vv[j].w);                                    \
    }                                                                              \
  } while (0)

__global__ __launch_bounds__(256) void aggregate(const unsigned short* __restrict__ xwp,
                                                 const float* __restrict__ dinv,
                                                 const int* __restrict__ row_ptr,
                                                 const unsigned short* __restrict__ csr16,
                                                 const float* __restrict__ bias,
                                                 float* __restrict__ out, int n) {
  const int node = (int)((blockIdx.x * blockDim.x + threadIdx.x) >> 6);
  const int lane = (int)(threadIdx.x & 63);
  if (node >= n) return;
  const int half = lane >> 5;                     // 0: even edges, 1: odd edges
  const int cl   = lane & 31;                     // 16 B column group
  const unsigned short* xb = xwp + cl * 8;        // + row*256 elems per gather

  float a0 = 0.f, a1 = 0.f, a2 = 0.f, a3 = 0.f, a4 = 0.f, a5 = 0.f, a6 = 0.f, a7 = 0.f;
  {  // self-loop row: accumulate in half 0 only (fold would double-count)
    uint4 v = *(const uint4*)(xb + ((size_t)node << 8));
    if (half == 0) {
      a0 = bflo(v.x); a1 = bfhi(v.x); a2 = bflo(v.y); a3 = bfhi(v.y);
      a4 = bflo(v.z); a5 = bfhi(v.z); a6 = bflo(v.w); a7 = bfhi(v.w);
    }
  }

  const int beg = row_ptr[node];
  const int end = row_ptr[node + 1];
  for (int base = beg; base < end; base += 64) {
    int idx = base + lane;
    int s = (idx < end) ? (int)csr16[idx] : n;    // sentinel -> zero row
    int m = end - base; if (m > 64) m = 64;
    int i = 0;
    for (; i + 16 <= m; i += 16) AGG_ACC(i, 8);   // 8 paired gathers, 16 edges
    if (i < m) {
      if (m - i <= 8) AGG_ACC(i, 4);              // short tail: 4 paired gathers
      else            AGG_ACC(i, 8);              // long tail, sentinel-padded
    }
  }

  // merge the two edge-halves
  a0 += __shfl_xor(a0, 32); a1 += __shfl_xor(a1, 32);
  a2 += __shfl_xor(a2, 32); a3 += __shfl_xor(a3, 32);
  a4 += __shfl_xor(a4, 32); a5 += __shfl_xor(a5, 32);
  a6 += __shfl_xor(a6, 32); a7 += __shfl_xor(a7, 32);

  // lane writes 4 floats at col cl*8 + half*4 (its own quarter of the row)
  const float s0 = half ? a4 : a0;
  const float s1 = half ? a5 : a1;
  const float s2 = half ? a6 : a2;
  const float s3 = half ? a7 : a3;
  const float dd = dinv[node];
  const float* bp = bias + cl * 8 + half * 4;
  f32x4 o;
  o.x = fmaxf(fmaf(s0, dd, bp[0]), 0.f);
  o.y = fmaxf(fmaf(s1, dd, bp[1]), 0.f);
  o.z = fmaxf(fmaf(s2, dd, bp[2]), 0.f);
  o.w = fmaxf(fmaf(s3, dd, bp[3]), 0.f);
  // NT store: 51 MB output, written once -- keep xwp in L2
  __builtin_nontemporal_store(o, (f32x4*)(out + (size_t)node * 256 + cl * 8 + half * 4));
}

// ---------------- launch ----------------

extern "C" void kernel_launch(void* const* d_in, const int* in_sizes, int n_in,
                              void* d_out, int out_size, void* d_ws, size_t ws_size,
                              hipStream_t stream) {
  const float* x  = (const float*)d_in[0];   // [n, 256]
  const int*   ei = (const int*)d_in[1];     // [2, E]
  const float* W  = (const float*)d_in[2];   // [256, 256]
  const float* b  = (const float*)d_in[3];   // [256]

  const int n = in_sizes[0] / FEATS;         // 50000
  const int E = in_sizes[1] / 2;             // 1,600,000
  const int* src = ei;
  const int* dst = ei + E;
  const int nbuck = (n + 255) >> 8;          // 196

  // workspace layout (bytes); xwp has n+1 rows (row n = zero sentinel)
  char* ws = (char*)d_ws;
  size_t o0 = 0;
  unsigned short* xwp    = (unsigned short*)(ws + o0); o0 += (size_t)(n + 1) * 512;
  unsigned short* Wt     = (unsigned short*)(ws + o0); o0 += 131072;
  float*          dinv   = (float*)(ws + o0);          o0 += 200064;
  int*            row_ptr = (int*)(ws + o0);           o0 += 200064;
  unsigned short* csr16  = (unsigned short*)(ws + o0); o0 += 3200000;
  int*            gcursor = (int*)(ws + o0);           o0 += 1024;
  int*            bbase   = (int*)(ws + o0);           o0 += 1024;
  unsigned*       temp    = (unsigned*)(ws + o0);      o0 += (size_t)MAXBUCK * BCAP * 4;
  // total ~37.4 MB

  // fused: W transpose (blocks 0-255) + gcursor zero + xwp sentinel row (block 256)
  hipLaunchKernelGGL(wt_init, dim3(257), dim3(256), 0, stream, W, Wt, gcursor, nbuck,
                     (unsigned*)(xwp + (size_t)n * 256));

  const int g_p1 = (E + 4095) / 4096;  // 391
  hipLaunchKernelGGL(pass1_bin, dim3(g_p1), dim3(1024), 0, stream, src, dst, E, nbuck, gcursor, temp);
  hipLaunchKernelGGL(scan_buckets, dim3(1), dim3(256), 0, stream, gcursor, bbase, row_ptr, nbuck, n);
  hipLaunchKernelGGL(pass2_csr, dim3(nbuck), dim3(1024), 0, stream, temp, gcursor, bbase,
                     csr16, row_ptr, dinv, n);

  hipLaunchKernelGGL(gemm_mfma, dim3((n + 63) / 64), dim3(256), 0, stream, x, Wt, dinv, xwp, n);

  const int g_agg = (n * 64 + 255) / 256;  // one wave per node
  hipLaunchKernelGGL(aggregate, dim3(g_agg), dim3(256), 0, stream,
                     xwp, dinv, row_ptr, csr16, b, (float*)d_out, n);
}